// Round 6
// baseline (1091.429 us; speedup 1.0000x reference)
//
#include <hip/hip_runtime.h>
#include <stdint.h>
#include <stddef.h>

#define H_DIM 512
#define M_DIM 4096
#define TOPK  64
#define BAND_CAP 192
#define KEEP_CAP 72
#define MARG 0.05f

typedef __attribute__((ext_vector_type(8))) short bf16x8;
typedef __attribute__((ext_vector_type(4))) float floatx4;
typedef __attribute__((ext_vector_type(8))) unsigned short ushort8;

static __device__ __forceinline__ unsigned short f2bf(float f) {
    union { float ff; unsigned int i; } v; v.ff = f;
    unsigned int u = v.i;
    u += 0x7FFFu + ((u >> 16) & 1u);   // RNE
    return (unsigned short)(u >> 16);
}

// ---- decT[m*H + h] = dec[h*M + m]  (fp32), for coalesced decode gathers
__global__ void sae_decT(const float* __restrict__ dec, float* __restrict__ decT) {
    int g = blockIdx.x * 256 + threadIdx.x;
    int m = g >> 9;            // / H_DIM
    int h = g & (H_DIM - 1);
    decT[g] = dec[(size_t)h * M_DIM + m];
}

// ---- K1: stored[n,m] = relu( bf16gemm(x - bpre, enc^T) + benc )  (fp32 out, unmasked)
__launch_bounds__(256, 2)
__global__ void sae_encode_gemm(const float* __restrict__ X,    // [N, H]
                                const float* __restrict__ Enc,  // [M, H]
                                const float* __restrict__ bpre, // [H]
                                const float* __restrict__ benc, // [M]
                                float* __restrict__ zbase)      // [N, M]
{
    __shared__ unsigned short lA[128 * 32];
    __shared__ unsigned short lB[128 * 32];
    const int tid  = threadIdx.x;
    const int lane = tid & 63;
    const int wave = tid >> 6;
    const int wx = wave & 1, wy = wave >> 1;
    const int mBase = blockIdx.x * 128;
    const int nBase = blockIdx.y * 128;

    floatx4 acc[4][4];
#pragma unroll
    for (int i = 0; i < 4; ++i)
#pragma unroll
        for (int j = 0; j < 4; ++j) acc[i][j] = (floatx4){0.f, 0.f, 0.f, 0.f};

    const int sRow = tid >> 1;
    const int sCol = (tid & 1) * 16;
    const size_t aRow = (size_t)(nBase + sRow) * H_DIM;
    const size_t bRow = (size_t)(mBase + sRow) * H_DIM;
    unsigned short* sA = &lA[sRow * 32 + sCol];
    unsigned short* sB = &lB[sRow * 32 + sCol];

    const int quad = lane >> 4;
    const int l15  = lane & 15;

    for (int kt = 0; kt < H_DIM / 32; ++kt) {
        const int k0 = kt * 32 + sCol;
        ushort8 wa0, wa1, wb0, wb1;
#pragma unroll
        for (int c = 0; c < 2; ++c) {
            float4 a0 = *(const float4*)(X + aRow + k0 + c * 8);
            float4 a1 = *(const float4*)(X + aRow + k0 + c * 8 + 4);
            float4 p0 = *(const float4*)(bpre + k0 + c * 8);
            float4 p1 = *(const float4*)(bpre + k0 + c * 8 + 4);
            float4 b0 = *(const float4*)(Enc + bRow + k0 + c * 8);
            float4 b1 = *(const float4*)(Enc + bRow + k0 + c * 8 + 4);
            ushort8 wa, wb;
            wa[0] = f2bf(a0.x - p0.x); wa[1] = f2bf(a0.y - p0.y);
            wa[2] = f2bf(a0.z - p0.z); wa[3] = f2bf(a0.w - p0.w);
            wa[4] = f2bf(a1.x - p1.x); wa[5] = f2bf(a1.y - p1.y);
            wa[6] = f2bf(a1.z - p1.z); wa[7] = f2bf(a1.w - p1.w);
            wb[0] = f2bf(b0.x); wb[1] = f2bf(b0.y); wb[2] = f2bf(b0.z); wb[3] = f2bf(b0.w);
            wb[4] = f2bf(b1.x); wb[5] = f2bf(b1.y); wb[6] = f2bf(b1.z); wb[7] = f2bf(b1.w);
            if (c == 0) { wa0 = wa; wb0 = wb; } else { wa1 = wa; wb1 = wb; }
        }
        __syncthreads();
        *(ushort8*)(sA)     = wa0;
        *(ushort8*)(sA + 8) = wa1;
        *(ushort8*)(sB)     = wb0;
        *(ushort8*)(sB + 8) = wb1;
        __syncthreads();
        bf16x8 af[4], bfr[4];
#pragma unroll
        for (int i = 0; i < 4; ++i)
            af[i] = *(const bf16x8*)&lA[(wy * 64 + i * 16 + l15) * 32 + quad * 8];
#pragma unroll
        for (int j = 0; j < 4; ++j)
            bfr[j] = *(const bf16x8*)&lB[(wx * 64 + j * 16 + l15) * 32 + quad * 8];
#pragma unroll
        for (int i = 0; i < 4; ++i)
#pragma unroll
            for (int j = 0; j < 4; ++j)
                acc[i][j] = __builtin_amdgcn_mfma_f32_16x16x32_bf16(af[i], bfr[j], acc[i][j], 0, 0, 0);
    }

#pragma unroll
    for (int i = 0; i < 4; ++i) {
        int nLoc = nBase + wy * 64 + i * 16 + quad * 4;
#pragma unroll
        for (int j = 0; j < 4; ++j) {
            int m = mBase + wx * 64 + j * 16 + l15;
            float bc = benc[m];
#pragma unroll
            for (int r = 0; r < 4; ++r) {
                float v = acc[i][j][r] + bc;
                v = v > 0.f ? v : 0.f;
                zbase[(size_t)(nLoc + r) * M_DIM + m] = v;
            }
        }
    }
}

// ---- K2 (fused): histogram top-64 select + masked write + sparse decode.
// Band values: EXACT round-5 arithmetic (single seq fp32 FMA chain k=0..511,
// ties within 0.6 ulp -> lower index). Block-uniform branches throughout.
__launch_bounds__(256, 2)
__global__ void sae_topk_decode(float* __restrict__ zbase,      // [N, M] in: logits, out: masked
                                const float* __restrict__ X,    // [N, H]
                                const float* __restrict__ Enc,  // [M, H]
                                const float* __restrict__ bpre, // [H]
                                const float* __restrict__ benc, // [M]
                                const float* __restrict__ dec,  // [H, M]
                                const float* __restrict__ decT, // [M, H] or null
                                float* __restrict__ xOut,       // [N, H]
                                int useDecT)
{
    __shared__ int   hist[4096];          // 16 KB (reused as wsum/scanb in fallback)
    __shared__ float xs[H_DIM];
    __shared__ int   bandIdx[BAND_CAP];
    __shared__ float bandVal[BAND_CAP];
    __shared__ int   keepIdx[KEEP_CAP];
    __shared__ float keepVal[KEEP_CAP];
    __shared__ int   sBand, sKeep, sD, sBinB, sTotal;

    const int tid  = threadIdx.x;
    const int lane = tid & 63;
    const int wave = tid >> 6;
    const int row  = blockIdx.x;

    if (tid == 0) { sBand = 0; sKeep = 0; sD = 0; sBinB = 0; sTotal = 0; }
    {
        int4* hz = (int4*)hist;
#pragma unroll
        for (int i = 0; i < 4; ++i) hz[tid * 4 + i] = (int4){0, 0, 0, 0};
    }

    // load the 16 owned values; stage xs = x - bias_pre
    float val[16];
    {
        const float4* src = (const float4*)(zbase + (size_t)row * M_DIM) + tid * 4;
#pragma unroll
        for (int i = 0; i < 4; ++i) {
            float4 t = src[i];
            val[i*4+0] = t.x; val[i*4+1] = t.y; val[i*4+2] = t.z; val[i*4+3] = t.w;
        }
        float2 xv = *(const float2*)(X + (size_t)row * H_DIM + tid * 2);
        float2 pv = *(const float2*)(bpre + tid * 2);
        xs[tid*2]   = xv.x - pv.x;
        xs[tid*2+1] = xv.y - pv.y;
    }
    unsigned int u[16];
#pragma unroll
    for (int i = 0; i < 16; ++i) u[i] = __float_as_uint(val[i]);
    __syncthreads();   // hist zeroed, scalars visible

    // histogram of positive values: bin = u >> 19 (exp<<4 | mant[22:19])
#pragma unroll
    for (int i = 0; i < 16; ++i)
        if (u[i]) atomicAdd(&hist[u[i] >> 19], 1);
    __syncthreads();

    // wave 0: per-lane 64-bin sums, suffix scan, locate rank-64 bin
    if (wave == 0) {
        const int base = lane * 64;
        int s = 0;
        const int4* hp = (const int4*)(hist + base);
#pragma unroll
        for (int i = 0; i < 16; ++i) { int4 h4 = hp[i]; s += h4.x + h4.y + h4.z + h4.w; }
        int suf = s;
#pragma unroll
        for (int off = 1; off < 64; off <<= 1) {
            int si = lane + off;
            int t = __shfl(suf, si < 64 ? si : lane);
            suf += (si < 64) ? t : 0;
        }
        if (lane == 0) sTotal = suf;
        int ni = lane + 1;
        int sufN = __shfl(suf, ni < 64 ? ni : lane);
        if (lane == 63) sufN = 0;
        if (suf >= TOPK && sufN < TOPK) {
            int cum = sufN;
            for (int i = 63; i >= 0; --i) {
                cum += hist[base + i];
                if (cum >= TOPK) { sBinB = base + i; break; }
            }
        }
    }
    __syncthreads();
    const int total = sTotal;

    if (total < TOPK) {
        // fewer than 64 positives: row already correct in memory; keep all positives
#pragma unroll
        for (int i = 0; i < 16; ++i) {
            if (val[i] > 0.f) {
                int p = atomicAdd(&sKeep, 1);
                if (p < KEEP_CAP) { keepIdx[p] = tid * 16 + i; keepVal[p] = val[i]; }
            }
        }
    } else {
        const int B = sBinB;
        const float binLo = __uint_as_float((unsigned)B << 19);
        const float binHi = __uint_as_float((unsigned)(B + 1) << 19);
        float lo = binLo - MARG; if (lo <= 0.f) lo = 1e-12f;
        const float hi = binHi + MARG;

        int dcnt = 0;
#pragma unroll
        for (int i = 0; i < 16; ++i) dcnt += (val[i] > hi) ? 1 : 0;
        if (dcnt) atomicAdd(&sD, dcnt);
#pragma unroll
        for (int i = 0; i < 16; ++i) {
            if (val[i] >= lo && val[i] <= hi) {
                int p = atomicAdd(&sBand, 1);
                if (p < BAND_CAP) bandIdx[p] = tid * 16 + i;
            } else if (val[i] > hi) {
                int p = atomicAdd(&sKeep, 1);
                if (p < KEEP_CAP) { keepIdx[p] = tid * 16 + i; keepVal[p] = val[i]; }
            }
        }
        __syncthreads();
        const int D  = sD;
        const int Bn = sBand;

        if (Bn <= BAND_CAP) {
            // np-exact band logits (round-5 proven arithmetic — DO NOT CHANGE)
            if (tid < Bn) {
                int m = bandIdx[tid];
                const float* er = Enc + (size_t)m * H_DIM;
                float s = 0.f;
#pragma unroll 8
                for (int k = 0; k < H_DIM; ++k) s = fmaf(xs[k], er[k], s);
                float lg = s + benc[m];
                bandVal[tid] = lg > 0.f ? lg : 0.f;
            }
            __syncthreads();

            int keepB = 0; float myV = 0.f; int myM = -1;
            if (tid < Bn) {
                myV = bandVal[tid]; myM = bandIdx[tid];
                const float eps = 7.2e-8f * myV;
                int r = 0;
                for (int k = 0; k < Bn; ++k) {
                    float v = bandVal[k];
                    float d = v - myV;
                    bool tie = (d <= eps) && (d >= -eps);
                    r += ((!tie && v > myV) || (tie && bandIdx[k] < myM)) ? 1 : 0;
                }
                if (r < TOPK - D) {
                    keepB = 1;
                    int p = atomicAdd(&sKeep, 1);
                    if (p < KEEP_CAP) { keepIdx[p] = myM; keepVal[p] = myV; }
                }
            }

            // bulk rewrite: definite keeps retain stored value, rest 0
            {
                float4* dst = (float4*)(zbase + (size_t)row * M_DIM) + tid * 4;
#pragma unroll
                for (int c = 0; c < 4; ++c) {
                    float4 t;
                    t.x = val[c*4+0] > hi ? val[c*4+0] : 0.f;
                    t.y = val[c*4+1] > hi ? val[c*4+1] : 0.f;
                    t.z = val[c*4+2] > hi ? val[c*4+2] : 0.f;
                    t.w = val[c*4+3] > hi ? val[c*4+3] : 0.f;
                    dst[c] = t;
                }
            }
            __syncthreads();   // order zero-writes before band scatter (WAW)
            if (keepB) zbase[(size_t)row * M_DIM + myM] = myV;
        } else {
            // fallback (≈ never): exact 31-pass bisection + stored-value quota
            unsigned int* wsum  = (unsigned int*)hist;
            unsigned int* scanb = (unsigned int*)hist + 8;
            unsigned int T = 0;
            for (int bit = 30; bit >= 0; --bit) {
                unsigned int cand = T | (1u << bit);
                int c = 0;
#pragma unroll
                for (int i = 0; i < 16; ++i) c += (u[i] >= cand) ? 1 : 0;
                for (int off = 32; off >= 1; off >>= 1) c += __shfl_down(c, off);
                __syncthreads();
                if (lane == 0) wsum[wave] = (unsigned int)c;
                __syncthreads();
                if (wsum[0] + wsum[1] + wsum[2] + wsum[3] >= TOPK) T = cand;
            }
            int c = 0;
#pragma unroll
            for (int i = 0; i < 16; ++i) c += (u[i] > T) ? 1 : 0;
            for (int off = 32; off >= 1; off >>= 1) c += __shfl_down(c, off);
            __syncthreads();
            if (lane == 0) wsum[wave] = (unsigned int)c;
            __syncthreads();
            unsigned int q = TOPK - (wsum[0] + wsum[1] + wsum[2] + wsum[3]);
            unsigned int myT = 0;
#pragma unroll
            for (int i = 0; i < 16; ++i) myT += (u[i] == T) ? 1u : 0u;
            scanb[tid] = myT;
            __syncthreads();
            if (tid == 0) {
                unsigned int run = 0;
                for (int t = 0; t < 256; ++t) { unsigned int c2 = scanb[t]; scanb[t] = run; run += c2; }
            }
            __syncthreads();
            unsigned int tieRank = scanb[tid];
#pragma unroll
            for (int i = 0; i < 16; ++i) {
                bool isTie = (u[i] == T);
                bool keep  = (u[i] > T) || (isTie && tieRank < q);
                if (isTie) tieRank++;
                zbase[(size_t)row * M_DIM + tid * 16 + i] = keep ? val[i] : 0.f;
                if (keep) {
                    int p = atomicAdd(&sKeep, 1);
                    if (p < KEEP_CAP) { keepIdx[p] = tid * 16 + i; keepVal[p] = val[i]; }
                }
            }
        }
    }
    __syncthreads();   // keep list complete

    // sparse decode: x[row, h] = sum_j keepVal[j] * decT[keepIdx[j], h] + bpre[h]
    int cnt = sKeep; if (cnt > KEEP_CAP) cnt = KEEP_CAP;
    const int h0 = tid * 2;
    float a0 = 0.f, a1 = 0.f;
    if (useDecT) {
#pragma unroll 4
        for (int j = 0; j < cnt; ++j) {
            float v = keepVal[j];
            int m   = keepIdx[j];
            float2 d = *(const float2*)(decT + (size_t)m * H_DIM + h0);
            a0 = fmaf(v, d.x, a0);
            a1 = fmaf(v, d.y, a1);
        }
    } else {
        for (int j = 0; j < cnt; ++j) {
            float v = keepVal[j];
            int m   = keepIdx[j];
            a0 = fmaf(v, dec[(size_t)h0 * M_DIM + m], a0);
            a1 = fmaf(v, dec[(size_t)(h0 + 1) * M_DIM + m], a1);
        }
    }
    float2 pv = *(const float2*)(bpre + h0);
    float2 o; o.x = a0 + pv.x; o.y = a1 + pv.y;
    *(float2*)(xOut + (size_t)row * H_DIM + h0) = o;
}

extern "C" void kernel_launch(void* const* d_in, const int* in_sizes, int n_in,
                              void* d_out, int out_size, void* d_ws, size_t ws_size,
                              hipStream_t stream)
{
    const float* zL   = (const float*)d_in[0]; // [N, H]
    const float* enc  = (const float*)d_in[1]; // [M, H]
    const float* dec  = (const float*)d_in[2]; // [H, M]
    const float* bpre = (const float*)d_in[3]; // [H]
    const float* benc = (const float*)d_in[4]; // [M]
    const int N = in_sizes[0] / H_DIM;         // 16384

    float* zOut = (float*)d_out;               // [N, M]
    float* xOut = zOut + (size_t)N * M_DIM;    // [N, H]

    float* decT = nullptr;
    int useDecT = 0;
    if (ws_size >= (size_t)M_DIM * H_DIM * 4) {
        decT = (float*)d_ws;
        useDecT = 1;
        sae_decT<<<(M_DIM * H_DIM) / 256, 256, 0, stream>>>(dec, decT);
    }

    sae_encode_gemm<<<dim3(M_DIM / 128, N / 128), 256, 0, stream>>>(zL, enc, bpre, benc, zOut);
    sae_topk_decode<<<N, 256, 0, stream>>>(zOut, zL, enc, bpre, benc, dec, decT, xOut, useDecT);
}